// Round 5
// baseline (85.069 us; speedup 1.0000x reference)
//
#include <hip/hip_runtime.h>

#define Q 4096
#define L 8192
#define RPB 8                  // ctx rows per block
#define NCB (L / RPB)          // 1024 ctx blocks
#define NKW 1024               // Kw first-half blocks (4 waves, 1 row/wave)

// ---------------------------------------------------------------------------
// K1 ctx blocks [0, NCB): no LDS staging, no inner barriers.
//   Phase 1: each thread dots its column slice (cols tid+k*256, k=0..3) of
//            all 8 rows against q  -> 32 independent 16B loads in flight.
//   One barrier: block-reduce the 8 scores.
//   Phase 2: per-block softmax weights, re-read rows (L2-hit), accumulate,
//            write one partial row + 8 raw scores.
// K1 Kw blocks [NCB, NCB+NKW): out1[i] = Kw[i, 0:Q] . q, one wave per row.
// ---------------------------------------------------------------------------
__global__ __launch_bounds__(256) void k1_kernel(
    const float* __restrict__ qvec, const float* __restrict__ ctx,
    const float* __restrict__ Kw, float* __restrict__ partial,
    float* __restrict__ score, float* __restrict__ out1)
{
    __shared__ float sred[4][RPB];     // 128 B
    const int tid  = threadIdx.x;
    const int lane = tid & 63;
    const int wid  = tid >> 6;

    if (blockIdx.x < NCB) {
        const float4* __restrict__ qg = (const float4*)qvec;
        const float4* __restrict__ cb = (const float4*)ctx;
        const int r0 = blockIdx.x * RPB;

        float4 qr[4];
        #pragma unroll
        for (int k = 0; k < 4; ++k) qr[k] = qg[tid + k * 256];

        // ---- phase 1: 8 per-thread dot partials, deep MLP ----
        float d[RPB];
        #pragma unroll
        for (int r = 0; r < RPB; ++r) {
            float a = 0.f;
            #pragma unroll
            for (int k = 0; k < 4; ++k) {
                float4 v = cb[(size_t)(r0 + r) * (Q / 4) + tid + k * 256];
                a = fmaf(v.x, qr[k].x, a); a = fmaf(v.y, qr[k].y, a);
                a = fmaf(v.z, qr[k].z, a); a = fmaf(v.w, qr[k].w, a);
            }
            d[r] = a;
        }
        #pragma unroll
        for (int r = 0; r < RPB; ++r) {
            float a = d[r];
            #pragma unroll
            for (int off = 32; off > 0; off >>= 1) a += __shfl_down(a, off, 64);
            if (lane == 0) sred[wid][r] = a;
        }
        __syncthreads();   // the ONLY block barrier

        // ---- block scores, per-block softmax weights ----
        float s[RPB], mb = -3.4e38f;
        #pragma unroll
        for (int r = 0; r < RPB; ++r) {
            s[r] = sred[0][r] + sred[1][r] + sred[2][r] + sred[3][r];
            mb = fmaxf(mb, s[r]);
        }
        float w[RPB];
        #pragma unroll
        for (int r = 0; r < RPB; ++r) w[r] = __expf(s[r] - mb);
        if (tid < RPB) {   // raw scores for K2
            score[r0 + tid] = sred[0][tid] + sred[1][tid] +
                              sred[2][tid] + sred[3][tid];
        }

        // ---- phase 2: re-read rows (L2-hit) and accumulate ----
        float4 acc[4];
        #pragma unroll
        for (int k = 0; k < 4; ++k) acc[k] = make_float4(0.f, 0.f, 0.f, 0.f);
        #pragma unroll
        for (int r = 0; r < RPB; ++r) {
            const float wr = w[r];
            #pragma unroll
            for (int k = 0; k < 4; ++k) {
                float4 v = cb[(size_t)(r0 + r) * (Q / 4) + tid + k * 256];
                acc[k].x = fmaf(wr, v.x, acc[k].x);
                acc[k].y = fmaf(wr, v.y, acc[k].y);
                acc[k].z = fmaf(wr, v.z, acc[k].z);
                acc[k].w = fmaf(wr, v.w, acc[k].w);
            }
        }
        float4* __restrict__ pb = (float4*)(partial + (size_t)blockIdx.x * Q);
        #pragma unroll
        for (int k = 0; k < 4; ++k) pb[tid + k * 256] = acc[k];
    } else {
        // ---- out1[i] = Kw[i, 0:Q] . q : one wave per row, barrier-free ----
        const int i = (blockIdx.x - NCB) * 4 + wid;      // 0..4095
        const float4* __restrict__ row = (const float4*)(Kw + (size_t)i * (2 * Q));
        const float4* __restrict__ qg  = (const float4*)qvec;
        float a0 = 0.f, a1 = 0.f, a2 = 0.f, a3 = 0.f;
        #pragma unroll
        for (int c = 0; c < 16; c += 4) {
            float4 x0 = row[(c + 0) * 64 + lane], y0 = qg[(c + 0) * 64 + lane];
            float4 x1 = row[(c + 1) * 64 + lane], y1 = qg[(c + 1) * 64 + lane];
            float4 x2 = row[(c + 2) * 64 + lane], y2 = qg[(c + 2) * 64 + lane];
            float4 x3 = row[(c + 3) * 64 + lane], y3 = qg[(c + 3) * 64 + lane];
            a0 = fmaf(x0.x, y0.x, a0); a0 = fmaf(x0.y, y0.y, a0);
            a0 = fmaf(x0.z, y0.z, a0); a0 = fmaf(x0.w, y0.w, a0);
            a1 = fmaf(x1.x, y1.x, a1); a1 = fmaf(x1.y, y1.y, a1);
            a1 = fmaf(x1.z, y1.z, a1); a1 = fmaf(x1.w, y1.w, a1);
            a2 = fmaf(x2.x, y2.x, a2); a2 = fmaf(x2.y, y2.y, a2);
            a2 = fmaf(x2.z, y2.z, a2); a2 = fmaf(x2.w, y2.w, a2);
            a3 = fmaf(x3.x, y3.x, a3); a3 = fmaf(x3.y, y3.y, a3);
            a3 = fmaf(x3.z, y3.z, a3); a3 = fmaf(x3.w, y3.w, a3);
        }
        float dd = (a0 + a1) + (a2 + a3);
        #pragma unroll
        for (int off = 32; off > 0; off >>= 1) dd += __shfl_down(dd, off, 64);
        if (lane == 0) out1[i] = dd;
    }
}

// ---------------------------------------------------------------------------
// K2: softmax stats from raw scores (redundant per block, score[] is L2-hot)
//     + merge NCB partials -> s_t.  128 blocks x 8 float4-columns.
// ---------------------------------------------------------------------------
__global__ __launch_bounds__(256) void k2_kernel(
    const float* __restrict__ partial, const float* __restrict__ score,
    float* __restrict__ s_t)
{
    __shared__ float wb[NCB];           // 4 KB
    __shared__ float red[4];
    __shared__ float4 sacc[32][8];      // 4 KB
    const int tid  = threadIdx.x;
    const int lane = tid & 63;
    const int wid  = tid >> 6;

    // global max M
    float lm = -3.4e38f;
    for (int i = tid; i < L; i += 256) lm = fmaxf(lm, score[i]);
    #pragma unroll
    for (int off = 32; off > 0; off >>= 1) lm = fmaxf(lm, __shfl_down(lm, off, 64));
    if (lane == 0) red[wid] = lm;
    __syncthreads();
    const float M = fmaxf(fmaxf(red[0], red[1]), fmaxf(red[2], red[3]));
    __syncthreads();

    // Z
    float lz = 0.f;
    for (int i = tid; i < L; i += 256) lz += __expf(score[i] - M);
    #pragma unroll
    for (int off = 32; off > 0; off >>= 1) lz += __shfl_down(lz, off, 64);
    if (lane == 0) red[wid] = lz;
    __syncthreads();
    const float invZ = 1.f / (red[0] + red[1] + red[2] + red[3]);

    // per-block weights: wb[b] = exp(max(score[8b..8b+7]) - M)
    for (int b = tid; b < NCB; b += 256) {
        const float4 sa = ((const float4*)score)[2 * b];
        const float4 sb = ((const float4*)score)[2 * b + 1];
        float m8 = fmaxf(fmaxf(fmaxf(sa.x, sa.y), fmaxf(sa.z, sa.w)),
                         fmaxf(fmaxf(sb.x, sb.y), fmaxf(sb.z, sb.w)));
        wb[b] = __expf(m8 - M);
    }
    __syncthreads();

    // weighted column sums: block owns 8 float4 columns, 32 b-groups
    const int c  = tid & 7;
    const int g  = tid >> 3;
    const int c4 = blockIdx.x * 8 + c;
    const float4* __restrict__ p = (const float4*)partial;
    float4 acc = make_float4(0.f, 0.f, 0.f, 0.f);
    for (int b = g; b < NCB; b += 32) {
        const float w = wb[b];
        float4 v = p[(size_t)b * (Q / 4) + c4];
        acc.x = fmaf(w, v.x, acc.x); acc.y = fmaf(w, v.y, acc.y);
        acc.z = fmaf(w, v.z, acc.z); acc.w = fmaf(w, v.w, acc.w);
    }
    sacc[g][c] = acc;
    __syncthreads();
    if (g == 0) {
        float4 t = sacc[0][c];
        #pragma unroll
        for (int gg = 1; gg < 32; ++gg) {
            float4 u = sacc[gg][c];
            t.x += u.x; t.y += u.y; t.z += u.z; t.w += u.w;
        }
        t.x *= invZ; t.y *= invZ; t.z *= invZ; t.w *= invZ;
        ((float4*)s_t)[c4] = t;
    }
}

// ---------------------------------------------------------------------------
// K3: out[i] = out1[i] + Kw[i, Q:2Q] . s_t   (one wave per row, no barriers)
// ---------------------------------------------------------------------------
__global__ __launch_bounds__(256) void k3_kernel(
    const float* __restrict__ Kw, const float* __restrict__ s_t,
    const float* __restrict__ out1, float* __restrict__ out)
{
    const int lane = threadIdx.x & 63;
    const int wid  = threadIdx.x >> 6;
    const int i = blockIdx.x * 4 + wid;
    const float4* __restrict__ row = (const float4*)(Kw + (size_t)i * (2 * Q) + Q);
    const float4* __restrict__ sg  = (const float4*)s_t;
    float a0 = 0.f, a1 = 0.f, a2 = 0.f, a3 = 0.f;
    #pragma unroll
    for (int c = 0; c < 16; c += 4) {
        float4 x0 = row[(c + 0) * 64 + lane], y0 = sg[(c + 0) * 64 + lane];
        float4 x1 = row[(c + 1) * 64 + lane], y1 = sg[(c + 1) * 64 + lane];
        float4 x2 = row[(c + 2) * 64 + lane], y2 = sg[(c + 2) * 64 + lane];
        float4 x3 = row[(c + 3) * 64 + lane], y3 = sg[(c + 3) * 64 + lane];
        a0 = fmaf(x0.x, y0.x, a0); a0 = fmaf(x0.y, y0.y, a0);
        a0 = fmaf(x0.z, y0.z, a0); a0 = fmaf(x0.w, y0.w, a0);
        a1 = fmaf(x1.x, y1.x, a1); a1 = fmaf(x1.y, y1.y, a1);
        a1 = fmaf(x1.z, y1.z, a1); a1 = fmaf(x1.w, y1.w, a1);
        a2 = fmaf(x2.x, y2.x, a2); a2 = fmaf(x2.y, y2.y, a2);
        a2 = fmaf(x2.z, y2.z, a2); a2 = fmaf(x2.w, y2.w, a2);
        a3 = fmaf(x3.x, y3.x, a3); a3 = fmaf(x3.y, y3.y, a3);
        a3 = fmaf(x3.z, y3.z, a3); a3 = fmaf(x3.w, y3.w, a3);
    }
    float dd = (a0 + a1) + (a2 + a3);
    #pragma unroll
    for (int off = 32; off > 0; off >>= 1) dd += __shfl_down(dd, off, 64);
    if (lane == 0) out[i] = out1[i] + dd;
}

// ---------------------------------------------------------------------------
extern "C" void kernel_launch(void* const* d_in, const int* in_sizes, int n_in,
                              void* d_out, int out_size, void* d_ws, size_t ws_size,
                              hipStream_t stream)
{
    const float* query = (const float*)d_in[0];   // [Q]
    const float* ctx   = (const float*)d_in[1];   // [L, Q]
    const float* Kw    = (const float*)d_in[2];   // [Q, 2Q]
    float* out = (float*)d_out;                   // [Q]

    // workspace layout (floats)
    float* ws      = (float*)d_ws;
    float* score   = ws;                          // L     = 8192
    float* out1    = ws + L;                      // Q     = 4096
    float* s_t     = ws + L + Q;                  // Q     = 4096
    float* partial = ws + L + 2 * Q;              // NCB*Q = 16 MiB

    k1_kernel<<<NCB + NKW, 256, 0, stream>>>(query, ctx, Kw, partial, score, out1);
    k2_kernel<<<Q / 4 / 8, 256, 0, stream>>>(partial, score, s_t);
    k3_kernel<<<Q / 4, 256, 0, stream>>>(Kw, s_t, out1, out);
}

// Round 6
// 70.663 us; speedup vs baseline: 1.2039x; 1.2039x over previous
//
#include <hip/hip_runtime.h>

#define Q 4096
#define L 8192
#define NCB 1024               // ctx blocks in K1
#define RPB (L / NCB)          // 8 rows per ctx block
#define NOB 256                // out1 blocks in K1 (4 waves each, 4 rows/wave)

// ---------------------------------------------------------------------------
// K1a (blocks 0..NCB-1): online softmax-weighted sum over 8 ctx rows.
//   vs round-3 (71.1us) version:  q lives in LDS (frees 16 VGPRs), next row
//   prefetched into a second register buffer while current row goes through
//   reduce/barrier/accumulate (hides load latency), sred double-buffered so
//   there is exactly one barrier per row.  Target VGPR <= 64.
// K1b (blocks NCB..NCB+NOB-1): out1[i] = Kw[i, 0:Q] . q (unchanged).
// ---------------------------------------------------------------------------
__global__ __launch_bounds__(256) void k1_kernel(
    const float* __restrict__ qvec, const float* __restrict__ ctx,
    const float* __restrict__ Kw,
    float* __restrict__ partial, float* __restrict__ m_arr,
    float* __restrict__ Z_arr, float* __restrict__ out1)
{
    __shared__ float4 qs4[Q / 4];      // 16 KB staged query
    __shared__ float sred[2][4];
    const int tid  = threadIdx.x;
    const int lane = tid & 63;
    const int wid  = tid >> 6;

    if (blockIdx.x < NCB) {
        const float4* __restrict__ qg = (const float4*)qvec;
        const float4* __restrict__ cb = (const float4*)ctx;
        const size_t base = (size_t)blockIdx.x * RPB * (Q / 4);

        // stage q into LDS (one barrier)
        #pragma unroll
        for (int k = 0; k < 4; ++k) qs4[tid + k * 256] = qg[tid + k * 256];
        __syncthreads();

        float4 va[4], vb[4];
        #pragma unroll
        for (int k = 0; k < 4; ++k) va[k] = cb[base + tid + k * 256];

        float4 acc[4];
        #pragma unroll
        for (int k = 0; k < 4; ++k) acc[k] = make_float4(0.f, 0.f, 0.f, 0.f);
        float m = -3.4e38f, Z = 0.f;

        // process(v, r): dot vs LDS q, 1-barrier reduce, online update
        #define PROCESS(V, R)                                                  \
        {                                                                      \
            float d = 0.f;                                                     \
            _Pragma("unroll")                                                  \
            for (int k = 0; k < 4; ++k) {                                      \
                const float4 qk = qs4[tid + k * 256];                          \
                d = fmaf((V)[k].x, qk.x, d); d = fmaf((V)[k].y, qk.y, d);      \
                d = fmaf((V)[k].z, qk.z, d); d = fmaf((V)[k].w, qk.w, d);      \
            }                                                                  \
            _Pragma("unroll")                                                  \
            for (int off = 32; off > 0; off >>= 1)                             \
                d += __shfl_down(d, off, 64);                                  \
            if (lane == 0) sred[(R) & 1][wid] = d;                             \
            __syncthreads();                                                   \
            const float s = sred[(R) & 1][0] + sred[(R) & 1][1] +              \
                            sred[(R) & 1][2] + sred[(R) & 1][3];               \
            if (s > m) {                                                       \
                const float sc = __expf(m - s);                                \
                Z *= sc;                                                       \
                _Pragma("unroll")                                              \
                for (int k = 0; k < 4; ++k) {                                  \
                    acc[k].x *= sc; acc[k].y *= sc;                            \
                    acc[k].z *= sc; acc[k].w *= sc;                            \
                }                                                              \
                m = s;                                                         \
            }                                                                  \
            const float w = __expf(s - m);                                     \
            Z += w;                                                            \
            _Pragma("unroll")                                                  \
            for (int k = 0; k < 4; ++k) {                                      \
                acc[k].x = fmaf(w, (V)[k].x, acc[k].x);                        \
                acc[k].y = fmaf(w, (V)[k].y, acc[k].y);                        \
                acc[k].z = fmaf(w, (V)[k].z, acc[k].z);                        \
                acc[k].w = fmaf(w, (V)[k].w, acc[k].w);                        \
            }                                                                  \
        }

        #pragma unroll
        for (int rp = 0; rp < RPB; rp += 2) {
            // prefetch row rp+1 while processing rp (in va)
            #pragma unroll
            for (int k = 0; k < 4; ++k)
                vb[k] = cb[base + (size_t)(rp + 1) * (Q / 4) + tid + k * 256];
            PROCESS(va, rp)
            // prefetch row rp+2 while processing rp+1 (in vb)
            if (rp + 2 < RPB) {
                #pragma unroll
                for (int k = 0; k < 4; ++k)
                    va[k] = cb[base + (size_t)(rp + 2) * (Q / 4) + tid + k * 256];
            }
            PROCESS(vb, rp + 1)
        }
        #undef PROCESS

        float4* __restrict__ pb = (float4*)(partial + (size_t)blockIdx.x * Q);
        #pragma unroll
        for (int k = 0; k < 4; ++k) pb[tid + k * 256] = acc[k];
        if (tid == 0) { m_arr[blockIdx.x] = m; Z_arr[blockIdx.x] = Z; }
    } else {
        // ---- out1 = Kw[:, 0:Q] . q, one wave per row, 4 rows per wave ----
        const int b = blockIdx.x - NCB;
        const float4* __restrict__ qv = (const float4*)qvec;
        for (int rr = 0; rr < 4; ++rr) {
            const int i = (b * 4 + wid) + rr * 1024;
            const float4* __restrict__ row = (const float4*)(Kw + (size_t)i * (2 * Q));
            float a = 0.f;
            #pragma unroll 4
            for (int it = 0; it < 16; ++it) {
                const int idx = it * 64 + lane;
                float4 x = row[idx], y = qv[idx];
                a = fmaf(x.x, y.x, a); a = fmaf(x.y, y.y, a);
                a = fmaf(x.z, y.z, a); a = fmaf(x.w, y.w, a);
            }
            #pragma unroll
            for (int off = 32; off > 0; off >>= 1) a += __shfl_down(a, off, 64);
            if (lane == 0) out1[i] = a;
        }
    }
}

// ---------------------------------------------------------------------------
// K2: merge the NCB partials:  s_t[j] = (1/Z_tot) * sum_b exp(m_b - M) * p_b[j]
//     64 blocks; each block owns 16 float4 columns; 16 b-groups sweep NCB.
//     (verbatim from the 71.1us config)
// ---------------------------------------------------------------------------
__global__ __launch_bounds__(256) void k2_kernel(
    const float* __restrict__ partial, const float* __restrict__ m_arr,
    const float* __restrict__ Z_arr, float* __restrict__ s_t)
{
    __shared__ float w_s[NCB];          // 4 KB
    __shared__ float redm[4];
    __shared__ float4 sacc[16][16];     // 4 KB
    const int tid  = threadIdx.x;
    const int lane = tid & 63;
    const int wid  = tid >> 6;

    // M = max_b m_b
    float lm = -3.4e38f;
    for (int b = tid; b < NCB; b += 256) lm = fmaxf(lm, m_arr[b]);
    #pragma unroll
    for (int off = 32; off > 0; off >>= 1) lm = fmaxf(lm, __shfl_down(lm, off, 64));
    if (lane == 0) redm[wid] = lm;
    __syncthreads();
    const float M = fmaxf(fmaxf(redm[0], redm[1]), fmaxf(redm[2], redm[3]));
    __syncthreads();

    // w_b and Z_tot
    float lz = 0.f;
    for (int b = tid; b < NCB; b += 256) {
        const float w = __expf(m_arr[b] - M);
        w_s[b] = w;
        lz = fmaf(w, Z_arr[b], lz);
    }
    #pragma unroll
    for (int off = 32; off > 0; off >>= 1) lz += __shfl_down(lz, off, 64);
    if (lane == 0) redm[wid] = lz;
    __syncthreads();
    const float invZ = 1.f / (redm[0] + redm[1] + redm[2] + redm[3]);

    // weighted column sums
    const int cidx = tid & 15;               // column within block
    const int g    = tid >> 4;               // 0..15 b-group
    const int c4   = blockIdx.x * 16 + cidx; // global float4 column
    const float4* __restrict__ p = (const float4*)partial;
    float4 acc = make_float4(0.f, 0.f, 0.f, 0.f);
    for (int b = g; b < NCB; b += 16) {
        const float w = w_s[b];
        float4 v = p[(size_t)b * (Q / 4) + c4];
        acc.x = fmaf(w, v.x, acc.x); acc.y = fmaf(w, v.y, acc.y);
        acc.z = fmaf(w, v.z, acc.z); acc.w = fmaf(w, v.w, acc.w);
    }
    sacc[g][cidx] = acc;
    __syncthreads();
    if (g == 0) {
        float4 t = sacc[0][cidx];
        #pragma unroll
        for (int gg = 1; gg < 16; ++gg) {
            float4 u = sacc[gg][cidx];
            t.x += u.x; t.y += u.y; t.z += u.z; t.w += u.w;
        }
        t.x *= invZ; t.y *= invZ; t.z *= invZ; t.w *= invZ;
        ((float4*)s_t)[c4] = t;
    }
}

// ---------------------------------------------------------------------------
// K3: out[i] = out1[i] + Kw[i, Q:2Q] . s_t    (one wave per row)
//     (verbatim from the 71.1us config)
// ---------------------------------------------------------------------------
__global__ __launch_bounds__(256) void k3_kernel(
    const float* __restrict__ Kw, const float* __restrict__ s_t,
    const float* __restrict__ out1, float* __restrict__ out)
{
    const int lane = threadIdx.x & 63;
    const int wid  = threadIdx.x >> 6;
    const int i = blockIdx.x * 4 + wid;
    const float4* __restrict__ row = (const float4*)(Kw + (size_t)i * (2 * Q) + Q);
    const float4* __restrict__ sv  = (const float4*)s_t;
    float a = 0.f;
    #pragma unroll 4
    for (int it = 0; it < 16; ++it) {
        const int idx = it * 64 + lane;
        float4 x = row[idx], y = sv[idx];
        a = fmaf(x.x, y.x, a); a = fmaf(x.y, y.y, a);
        a = fmaf(x.z, y.z, a); a = fmaf(x.w, y.w, a);
    }
    #pragma unroll
    for (int off = 32; off > 0; off >>= 1) a += __shfl_down(a, off, 64);
    if (lane == 0) out[i] = out1[i] + a;
}

// ---------------------------------------------------------------------------
extern "C" void kernel_launch(void* const* d_in, const int* in_sizes, int n_in,
                              void* d_out, int out_size, void* d_ws, size_t ws_size,
                              hipStream_t stream)
{
    const float* query = (const float*)d_in[0];   // [Q]
    const float* ctx   = (const float*)d_in[1];   // [L, Q]
    const float* Kw    = (const float*)d_in[2];   // [Q, 2Q]
    float* out = (float*)d_out;                   // [Q]

    // workspace layout (floats)
    float* ws      = (float*)d_ws;
    float* m_arr   = ws;                          // NCB   = 1024
    float* Z_arr   = ws + NCB;                    // NCB   = 1024
    float* out1    = ws + 2 * NCB;                // Q     = 4096
    float* s_t     = ws + 2 * NCB + Q;            // Q     = 4096
    float* partial = ws + 2 * NCB + 2 * Q;        // NCB*Q = 16 MiB

    k1_kernel<<<NCB + NOB, 256, 0, stream>>>(query, ctx, Kw,
                                             partial, m_arr, Z_arr, out1);
    k2_kernel<<<Q / 4 / 16, 256, 0, stream>>>(partial, m_arr, Z_arr, s_t);
    k3_kernel<<<Q / 4, 256, 0, stream>>>(Kw, s_t, out1, out);
}